// Round 9
// baseline (355.536 us; speedup 1.0000x reference)
//
#include <hip/hip_runtime.h>
#include <hip/hip_bf16.h>

// ============================================================================
// Head: K=x@Wk^T, Q=x@Wq^T, V=x@Wv^T, causal softmax(QK^T/8)@V
// B=4, T=4096, D=1024, H=64. fp32 I/O, bf16 MFMA compute.
//
// R14 = R13 resubmit (round 8 died to broker capacity, never measured).
// R13 = R12 (verified 347.4us; attn 193us, Mfma 20.5 / VALU 29.6 / Occ 24.4)
// with ONE attn change: 16-wave blocks (1024 thr), each wave owns 16 q-rows.
//  Why: 128 regs/wave caps the CU at 16 waves; 8-wave blocks leave the CU at
//  2 waves/SIMD once the light pair-block drains (measured Occ 24.4%). Same
//  grid/LDS/schedule, acc [2][8]->[1][8] (64->32 AGPR), 4 waves/SIMD for the
//  whole kernel. Zero added work, plain-C index re-partition only.
//
// FENCED (R6=NaN / R11=3.6e5): {v_cvt_pk_bf16_f32 asm, __builtin_amdgcn_exp2f,
// s_setprio} in attn_fa — register/LDS corruption at the 128-reg wall.
// Dead: V-in-registers (R10 spills); 64-row 4-wave blocks (R9 drain-out).
// ============================================================================

typedef __attribute__((ext_vector_type(8))) short bf16x8;   // 8 bf16, 4 VGPRs
typedef __attribute__((ext_vector_type(4))) float f32x4;

typedef unsigned short u16;
typedef unsigned int u32;

__device__ inline u16 f2bf(float f) {
    u32 u = __builtin_bit_cast(u32, f);
    u = (u + 0x7fff + ((u >> 16) & 1)) >> 16;   // RNE
    return (u16)u;
}

__device__ inline u32 pkbf(float a, float b) {  // bf16(a) | bf16(b)<<16
    return (u32)f2bf(a) | ((u32)f2bf(b) << 16);
}

__device__ inline void g2lds16(const void* g, void* l) {
    __builtin_amdgcn_global_load_lds(
        (const __attribute__((address_space(1))) unsigned int*)g,
        (__attribute__((address_space(3))) unsigned int*)l, 16, 0, 0);
}

// Fragment-tile addressing (16 rows x 32 k, 512 u16 = 1KB per tile):
//   element (r, k): u16 idx = ((r&15) + ((k>>3)&3)*16)*8 + (k&7)
// A-frag (m=lane&15, k=quad*8+j) and B-frag (n=lane&15, k=quad*8+j) reads are
// both "base + lane*16B" -> coalesced global / conflict-free LDS.

// ----------------------------------------------------------------------------
__global__ void cvt_x(const float* __restrict__ src, u16* __restrict__ dst,
                      int n) {
    const int i = (blockIdx.x * blockDim.x + threadIdx.x) * 8;
    if (i + 7 < n) {
        const float4 a = *(const float4*)(src + i);
        const float4 b = *(const float4*)(src + i + 4);
        u32 r[4];
        r[0] = pkbf(a.x, a.y);
        r[1] = pkbf(a.z, a.w);
        r[2] = pkbf(b.x, b.y);
        r[3] = pkbf(b.z, b.w);
        *(uint4*)(dst + i) = *(const uint4*)r;
    }
}

// Fused weight convert: Wk (1x), Wq (x 0.125*log2e), Wv (1x).
__global__ void cvt_w(const float* __restrict__ Wk, const float* __restrict__ Wq,
                      const float* __restrict__ Wv,
                      u16* __restrict__ Wkb, u16* __restrict__ Wqb,
                      u16* __restrict__ Wvb, float qscale) {
    const int i = (blockIdx.x * blockDim.x + threadIdx.x) * 8;
    const float* src; u16* dst; int j; float s = 1.0f;
    if (i < 65536)        { src = Wk; dst = Wkb; j = i; }
    else if (i < 131072)  { src = Wq; dst = Wqb; j = i - 65536; s = qscale; }
    else                  { src = Wv; dst = Wvb; j = i - 131072; }
    const float4 a = *(const float4*)(src + j);
    const float4 b = *(const float4*)(src + j + 4);
    u32 r[4];
    r[0] = pkbf(a.x * s, a.y * s);
    r[1] = pkbf(a.z * s, a.w * s);
    r[2] = pkbf(b.x * s, b.y * s);
    r[3] = pkbf(b.z * s, b.w * s);
    *(uint4*)(dst + j) = *(const uint4*)r;
}

// ----------------------------------------------------------------------------
// GEMM body: C = A[M][K] @ Bsel[N][K]^T, bf16, fp32 accum, 128x128, BK=64.
// lda = ldb = K = 1024. Outputs frag-tiled (MODE 1: Qf/Kf, MODE 2: Vf).
// ----------------------------------------------------------------------------
template <int MODE>
__device__ __forceinline__ void gemm_body(
    int m0, int n0,
    const u16* __restrict__ A,
    const u16* __restrict__ B0, const u16* __restrict__ B1, int nsplit,
    u16* __restrict__ D0, u16* __restrict__ D1,
    u16* Alds, u16* Blds)
{
    const int tid  = threadIdx.x;
    const int lane = tid & 63, w = tid >> 6;
    const int quad = lane >> 4, l15 = lane & 15;
    const int wr = w >> 1, wc = w & 1;
    const int mrow0 = wr * 64, ncol0 = wc * 64;

    f32x4 acc[4][4] = {};

    const int srow = (lane >> 3);
    const int scol = (lane & 7) * 8;

    for (int k0 = 0; k0 < 1024; k0 += 64) {
        __syncthreads();
#pragma unroll
        for (int c = 0; c < 4; ++c) {
            const int chunk = c * 4 + w;
            const int row = chunk * 8 + srow;
            const u16* ga = A + (size_t)(m0 + row) * 1024 + k0 + scol;
            g2lds16(ga, &Alds[chunk * 512]);
            const int brow = n0 + row;
            const u16* gb = (brow < nsplit ? B0 + (size_t)brow * 1024
                                           : B1 + (size_t)(brow - nsplit) * 1024)
                            + k0 + scol;
            g2lds16(gb, &Blds[chunk * 512]);
        }
        __syncthreads();

#pragma unroll
        for (int kk = 0; kk < 64; kk += 32) {
            bf16x8 af[4], bfr[4];
#pragma unroll
            for (int mb = 0; mb < 4; ++mb)
                af[mb] = *(const bf16x8*)&Alds[(mrow0 + mb * 16 + l15) * 64 + kk + quad * 8];
#pragma unroll
            for (int nb = 0; nb < 4; ++nb)
                bfr[nb] = *(const bf16x8*)&Blds[(ncol0 + nb * 16 + l15) * 64 + kk + quad * 8];
#pragma unroll
            for (int mb = 0; mb < 4; ++mb)
#pragma unroll
                for (int nb = 0; nb < 4; ++nb)
                    acc[mb][nb] = __builtin_amdgcn_mfma_f32_16x16x32_bf16(
                        af[mb], bfr[nb], acc[mb][nb], 0, 0, 0);
        }
    }

    // epilogue: C/D layout col=lane&15, row=quad*4+reg
#pragma unroll
    for (int mb = 0; mb < 4; ++mb)
#pragma unroll
        for (int nb = 0; nb < 4; ++nb)
#pragma unroll
            for (int r = 0; r < 4; ++r) {
                const int row = m0 + mrow0 + mb * 16 + quad * 4 + r;
                const int col = n0 + ncol0 + nb * 16 + l15;
                const u16 v = f2bf(acc[mb][nb][r]);
                if (MODE == 1) {
                    const int h = col & 63;
                    u16* dst = (col < 64) ? D0 : D1;
                    const size_t idx = (size_t)((row >> 4) * 2 + (h >> 5)) * 512
                                     + ((row & 15) + ((h >> 3) & 3) * 16) * 8
                                     + (h & 7);
                    dst[idx] = v;
                } else {
                    const size_t idx = (size_t)((row >> 4) * 512 + (col >> 5)) * 512
                                     + ((row & 15) + ((col >> 3) & 3) * 16) * 8
                                     + (col & 7);
                    D0[idx] = v;
                }
            }
}

// Combined GEMM dispatch: blocks [0,128) -> QK projection, [128,1152) -> Vt.
__global__ __launch_bounds__(256, 2) void gemm_all(
    const u16* __restrict__ xb,
    const u16* __restrict__ Wqb, const u16* __restrict__ Wkb,
    const u16* __restrict__ Wvb,
    u16* __restrict__ Qf, u16* __restrict__ Kf, u16* __restrict__ Vf)
{
    __shared__ u16 Alds[128 * 64];
    __shared__ u16 Blds[128 * 64];
    const int d = blockIdx.x;
    if (d < 128) {
        gemm_body<1>(d * 128, 0, xb, Wqb, Wkb, 64, Qf, Kf, Alds, Blds);
    } else {
        const int dd = d - 128;
        gemm_body<2>((dd >> 7) * 128, (dd & 127) * 128, Wvb, xb, xb, 1 << 30,
                     Vf, nullptr, Alds, Blds);
    }
}

// ----------------------------------------------------------------------------
// Flash attention, no-max softmax, es-split P handoff, software-pipelined.
// grid (128,4) flat d: g=d>>4, qt = g<16 ? 31-g : g-16 (complementary pairs),
// e0 = ((d>>2)&3)*256, b = d&3. Block 1024 thr (16 waves): wave w ->
// qs=w>>1 (16 q rows), es=w&1 (phase A: 16 s-cols of S; phase B: 128 e cols).
// Iter order identical to R5/R12: barrier -> stageV(it+1) -> loadK(it+1) ->
// PV(it) -> computeP(it+1).
// ----------------------------------------------------------------------------
__global__ __launch_bounds__(1024, 4) void attn_fa(
    const u16* __restrict__ Qf,
    const u16* __restrict__ Kf,
    const u16* __restrict__ Vf,
    float* __restrict__ Out)
{
    __shared__ u16 Vlds[2][16 * 512];   // 2 x 16KB (e=256, s=32)
    __shared__ u16 Plds[2][128 * 40];   // 2 x 10KB block-shared P, row-pad 40

    const int tid  = threadIdx.x;
    const int lane = tid & 63, w = tid >> 6;      // w in [0,16)
    const int quad = lane >> 4, l15 = lane & 15;

    const int d  = blockIdx.y * 128 + blockIdx.x;
    const int g  = d >> 4;
    const int qt = (g < 16) ? (31 - g) : (g - 16);
    const int e0 = ((d >> 2) & 3) * 256;
    const int b  = d & 3;
    const int bt0 = b * 4096;

    const int qs = w >> 1, es = w & 1;            // qs in [0,8): 16 rows each
    const int qrow0 = qt * 128 + qs * 16;

    // Q A-frags (persistent, log2-domain scaled): one 16-row tile, K=64
    bf16x8 qf[2];
    {
        const int btile = (bt0 + qrow0) >> 4;
#pragma unroll
        for (int kk = 0; kk < 2; ++kk)
            qf[kk] = *(const bf16x8*)&Qf[(size_t)(btile * 2 + kk) * 512 + lane * 8];
    }

    // ones B-fragment for row-sum accumulation (bf16 1.0 = 0x3F80)
    const short o = (short)0x3F80;
    const bf16x8 ones = {o, o, o, o, o, o, o, o};

    f32x4 acc[8] = {};      // O accumulator [nb_e]
    f32x4 accl = {};        // row-sum accumulator

    const int ntiles = 4 * qt + 4;
    const int qlim = qrow0 + 15;        // wave active for tile it iff it*32 <= qlim

    // ---- stage V tile `it` into Vlds[buf]: one 1KB slice per wave ----
    auto stageV = [&](int buf, int it) {
        const int stile = (bt0 + it * 32) >> 5;
        g2lds16(&Vf[(size_t)(((e0 >> 4) + w) * 512 + stile) * 512 + lane * 8],
                &Vlds[buf][w * 512]);
    };

    // ---- load this wave's K half for tile `jt` (2 x b128 global) ----
    auto loadK = [&](int jt, bf16x8* kf) {
#pragma unroll
        for (int kk = 0; kk < 2; ++kk) {
            const int kt = ((bt0 + jt * 32 + es * 16) >> 4) * 2 + kk;
            kf[kk] = *(const bf16x8*)&Kf[(size_t)kt * 512 + lane * 8];
        }
    };

    // ---- compute this wave's quarter of P(jt) into Plds[jt&1] ----
    // (16 q rows x 16 s cols; the 2 es waves of a qs pair cover 16x32)
    auto computeP = [&](int jt, const bf16x8* kf) {
        const int s0 = jt * 32;
        f32x4 sf = {};
#pragma unroll
        for (int kk = 0; kk < 2; ++kk)
            sf = __builtin_amdgcn_mfma_f32_16x16x32_bf16(qf[kk], kf[kk], sf, 0, 0, 0);
        if (s0 + 31 > qrow0) {          // diagonal-crossing: mask
            const int colabs = s0 + es * 16 + l15;
#pragma unroll
            for (int r = 0; r < 4; ++r) {
                const int rowabs = qrow0 + quad * 4 + r;
                sf[r] = (colabs <= rowabs) ? sf[r] : -__builtin_inff();
            }
        }
        u16* Pl = &Plds[jt & 1][(qs * 16 + quad * 4) * 40 + es * 16 + l15];
        const u32 p01 = pkbf(exp2f(sf[0]), exp2f(sf[1]));
        const u32 p23 = pkbf(exp2f(sf[2]), exp2f(sf[3]));
        Pl[0]   = (u16)p01;
        Pl[40]  = (u16)(p01 >> 16);
        Pl[80]  = (u16)p23;
        Pl[120] = (u16)(p23 >> 16);
    };

    // ---- prologue: tile 0 ----
    stageV(0, 0);
    {
        bf16x8 kf0[2];
        loadK(0, kf0);
        computeP(0, kf0);
    }

    for (int it = 0; it < ntiles; ++it) {
        __syncthreads();                 // V(it), P(it) ready (vmcnt drained)
        const int buf = it & 1;
        const bool haveNext = (it + 1 < ntiles);
        const bool nextActive = haveNext && ((it + 1) * 32 <= qlim);
        const bool curActive = (it * 32 <= qlim);

        if (haveNext) stageV(buf ^ 1, it + 1);
        bf16x8 kf[2];
        if (nextActive) loadK(it + 1, kf);

        if (curActive) {
            // ---- O += P @ V ; l += P @ 1 ----
            const bf16x8 pf = *(const bf16x8*)&Plds[buf][(qs * 16 + l15) * 40 + quad * 8];
            accl = __builtin_amdgcn_mfma_f32_16x16x32_bf16(pf, ones, accl, 0, 0, 0);
#pragma unroll
            for (int nb = 0; nb < 8; ++nb) {
                bf16x8 vf = *(const bf16x8*)&Vlds[buf][(es * 8 + nb) * 512 + lane * 8];
                acc[nb] = __builtin_amdgcn_mfma_f32_16x16x32_bf16(
                    pf, vf, acc[nb], 0, 0, 0);
            }
        }

        if (nextActive) computeP(it + 1, kf);
    }

    // ---- epilogue: normalize by row sums ----
    float rl[4];
#pragma unroll
    for (int r = 0; r < 4; ++r) rl[r] = 1.0f / accl[r];
#pragma unroll
    for (int nb = 0; nb < 8; ++nb)
#pragma unroll
        for (int r = 0; r < 4; ++r) {
            const int row = qrow0 + quad * 4 + r;
            const int col = e0 + es * 128 + nb * 16 + l15;
            Out[(size_t)(bt0 + row) * 1024 + col] = acc[nb][r] * rl[r];
        }
}

// ----------------------------------------------------------------------------
extern "C" void kernel_launch(void* const* d_in, const int* in_sizes, int n_in,
                              void* d_out, int out_size, void* d_ws, size_t ws_size,
                              hipStream_t stream) {
    const float* x  = (const float*)d_in[0];   // [4,4096,1024]
    const float* Wk = (const float*)d_in[1];   // [64,1024]
    const float* Wq = (const float*)d_in[2];   // [64,1024]
    const float* Wv = (const float*)d_in[3];   // [1024,1024]

    const int nx  = in_sizes[0];
    const int nwk = in_sizes[1];
    const int nwq = in_sizes[2];
    const int nwv = in_sizes[3];

    u16* xb  = (u16*)d_ws;
    u16* Wkb = xb  + (size_t)nx;
    u16* Wqb = Wkb + (size_t)nwk;
    u16* Wvb = Wqb + (size_t)nwq;
    u16* Qf  = Wvb + (size_t)nwv;                    // 1024 btiles * 2 * 512
    u16* Kf  = Qf  + (size_t)1024 * 2 * 512;
    u16* Vf  = Kf  + (size_t)1024 * 2 * 512;         // 64 etiles * 512 * 512
    float* out = (float*)d_out;

    const float qscale = 0.125f * 1.44269504088896f; // fold 1/sqrt(H)*log2(e)

    cvt_x<<<nx / 2048, 256, 0, stream>>>(x, xb, nx);
    cvt_w<<<(nwk + nwq + nwv) / 2048, 256, 0, stream>>>(Wk, Wq, Wv,
                                                        Wkb, Wqb, Wvb, qscale);

    gemm_all<<<1152, 256, 0, stream>>>(xb, Wqb, Wkb, Wvb, Qf, Kf, Vf);

    attn_fa<<<dim3(128, 4), 1024, 0, stream>>>(Qf, Kf, Vf, out);
}

// Round 11
// 340.689 us; speedup vs baseline: 1.0436x; 1.0436x over previous
//
#include <hip/hip_runtime.h>
#include <hip/hip_bf16.h>

// ============================================================================
// Head: K=x@Wk^T, Q=x@Wq^T, V=x@Wv^T, causal softmax(QK^T/8)@V
// B=4, T=4096, D=1024, H=64. fp32 I/O, bf16 MFMA compute.
//
// R16 = R15 resubmit (round 10 died to broker capacity, never measured).
// R15 = R14 (verified 355.5us; attn 200.7us, Mfma 19.5 / VALU 32.4 / Occ 37.2)
// with ONE change: s-tile 32 -> 64 (ntiles = 2qt+2, half the iterations).
//  Why: R12(8w,Occ24)=193us vs R14(16w,Occ37)=200us proved occupancy is NOT
//  the limiter; per-iter cost ~3640cyc vs ~180cyc MFMA issue => barrier-convoy
//  / per-iter overhead bound. Bigger tile amortizes barrier+drain+addressing
//  over 2x work and doubles the K-prefetch hiding window.
//  LDS 52->100KB (Vlds 2x32KB + Plds 2x128x72; gfx950 allows up to 160KB,
//  cf. verified 128KB 8-phase example). kf[2]->kf[4] (~100 regs < 128 cap).
//
// FENCED (R6=NaN / R11=3.6e5): {v_cvt_pk_bf16_f32 asm, __builtin_amdgcn_exp2f,
// s_setprio} in attn_fa — register/LDS corruption at the 128-reg wall.
// Dead: V-in-registers (R10 spills); 64-row 4-wave blocks (R9 drain-out);
// more waves (R13/R14: +50% occupancy, 0% speedup).
// ============================================================================

typedef __attribute__((ext_vector_type(8))) short bf16x8;   // 8 bf16, 4 VGPRs
typedef __attribute__((ext_vector_type(4))) float f32x4;

typedef unsigned short u16;
typedef unsigned int u32;

__device__ inline u16 f2bf(float f) {
    u32 u = __builtin_bit_cast(u32, f);
    u = (u + 0x7fff + ((u >> 16) & 1)) >> 16;   // RNE
    return (u16)u;
}

__device__ inline u32 pkbf(float a, float b) {  // bf16(a) | bf16(b)<<16
    return (u32)f2bf(a) | ((u32)f2bf(b) << 16);
}

__device__ inline void g2lds16(const void* g, void* l) {
    __builtin_amdgcn_global_load_lds(
        (const __attribute__((address_space(1))) unsigned int*)g,
        (__attribute__((address_space(3))) unsigned int*)l, 16, 0, 0);
}

// Fragment-tile addressing (16 rows x 32 k, 512 u16 = 1KB per tile):
//   element (r, k): u16 idx = ((r&15) + ((k>>3)&3)*16)*8 + (k&7)
// A-frag (m=lane&15, k=quad*8+j) and B-frag (n=lane&15, k=quad*8+j) reads are
// both "base + lane*16B" -> coalesced global / conflict-free LDS.

// ----------------------------------------------------------------------------
__global__ void cvt_x(const float* __restrict__ src, u16* __restrict__ dst,
                      int n) {
    const int i = (blockIdx.x * blockDim.x + threadIdx.x) * 8;
    if (i + 7 < n) {
        const float4 a = *(const float4*)(src + i);
        const float4 b = *(const float4*)(src + i + 4);
        u32 r[4];
        r[0] = pkbf(a.x, a.y);
        r[1] = pkbf(a.z, a.w);
        r[2] = pkbf(b.x, b.y);
        r[3] = pkbf(b.z, b.w);
        *(uint4*)(dst + i) = *(const uint4*)r;
    }
}

// Fused weight convert: Wk (1x), Wq (x 0.125*log2e), Wv (1x).
__global__ void cvt_w(const float* __restrict__ Wk, const float* __restrict__ Wq,
                      const float* __restrict__ Wv,
                      u16* __restrict__ Wkb, u16* __restrict__ Wqb,
                      u16* __restrict__ Wvb, float qscale) {
    const int i = (blockIdx.x * blockDim.x + threadIdx.x) * 8;
    const float* src; u16* dst; int j; float s = 1.0f;
    if (i < 65536)        { src = Wk; dst = Wkb; j = i; }
    else if (i < 131072)  { src = Wq; dst = Wqb; j = i - 65536; s = qscale; }
    else                  { src = Wv; dst = Wvb; j = i - 131072; }
    const float4 a = *(const float4*)(src + j);
    const float4 b = *(const float4*)(src + j + 4);
    u32 r[4];
    r[0] = pkbf(a.x * s, a.y * s);
    r[1] = pkbf(a.z * s, a.w * s);
    r[2] = pkbf(b.x * s, b.y * s);
    r[3] = pkbf(b.z * s, b.w * s);
    *(uint4*)(dst + j) = *(const uint4*)r;
}

// ----------------------------------------------------------------------------
// GEMM body: C = A[M][K] @ Bsel[N][K]^T, bf16, fp32 accum, 128x128, BK=64.
// lda = ldb = K = 1024. Outputs frag-tiled (MODE 1: Qf/Kf, MODE 2: Vf).
// ----------------------------------------------------------------------------
template <int MODE>
__device__ __forceinline__ void gemm_body(
    int m0, int n0,
    const u16* __restrict__ A,
    const u16* __restrict__ B0, const u16* __restrict__ B1, int nsplit,
    u16* __restrict__ D0, u16* __restrict__ D1,
    u16* Alds, u16* Blds)
{
    const int tid  = threadIdx.x;
    const int lane = tid & 63, w = tid >> 6;
    const int quad = lane >> 4, l15 = lane & 15;
    const int wr = w >> 1, wc = w & 1;
    const int mrow0 = wr * 64, ncol0 = wc * 64;

    f32x4 acc[4][4] = {};

    const int srow = (lane >> 3);
    const int scol = (lane & 7) * 8;

    for (int k0 = 0; k0 < 1024; k0 += 64) {
        __syncthreads();
#pragma unroll
        for (int c = 0; c < 4; ++c) {
            const int chunk = c * 4 + w;
            const int row = chunk * 8 + srow;
            const u16* ga = A + (size_t)(m0 + row) * 1024 + k0 + scol;
            g2lds16(ga, &Alds[chunk * 512]);
            const int brow = n0 + row;
            const u16* gb = (brow < nsplit ? B0 + (size_t)brow * 1024
                                           : B1 + (size_t)(brow - nsplit) * 1024)
                            + k0 + scol;
            g2lds16(gb, &Blds[chunk * 512]);
        }
        __syncthreads();

#pragma unroll
        for (int kk = 0; kk < 64; kk += 32) {
            bf16x8 af[4], bfr[4];
#pragma unroll
            for (int mb = 0; mb < 4; ++mb)
                af[mb] = *(const bf16x8*)&Alds[(mrow0 + mb * 16 + l15) * 64 + kk + quad * 8];
#pragma unroll
            for (int nb = 0; nb < 4; ++nb)
                bfr[nb] = *(const bf16x8*)&Blds[(ncol0 + nb * 16 + l15) * 64 + kk + quad * 8];
#pragma unroll
            for (int mb = 0; mb < 4; ++mb)
#pragma unroll
                for (int nb = 0; nb < 4; ++nb)
                    acc[mb][nb] = __builtin_amdgcn_mfma_f32_16x16x32_bf16(
                        af[mb], bfr[nb], acc[mb][nb], 0, 0, 0);
        }
    }

    // epilogue: C/D layout col=lane&15, row=quad*4+reg
#pragma unroll
    for (int mb = 0; mb < 4; ++mb)
#pragma unroll
        for (int nb = 0; nb < 4; ++nb)
#pragma unroll
            for (int r = 0; r < 4; ++r) {
                const int row = m0 + mrow0 + mb * 16 + quad * 4 + r;
                const int col = n0 + ncol0 + nb * 16 + l15;
                const u16 v = f2bf(acc[mb][nb][r]);
                if (MODE == 1) {
                    const int h = col & 63;
                    u16* dst = (col < 64) ? D0 : D1;
                    const size_t idx = (size_t)((row >> 4) * 2 + (h >> 5)) * 512
                                     + ((row & 15) + ((h >> 3) & 3) * 16) * 8
                                     + (h & 7);
                    dst[idx] = v;
                } else {
                    const size_t idx = (size_t)((row >> 4) * 512 + (col >> 5)) * 512
                                     + ((row & 15) + ((col >> 3) & 3) * 16) * 8
                                     + (col & 7);
                    D0[idx] = v;
                }
            }
}

// Combined GEMM dispatch: blocks [0,128) -> QK projection, [128,1152) -> Vt.
__global__ __launch_bounds__(256, 2) void gemm_all(
    const u16* __restrict__ xb,
    const u16* __restrict__ Wqb, const u16* __restrict__ Wkb,
    const u16* __restrict__ Wvb,
    u16* __restrict__ Qf, u16* __restrict__ Kf, u16* __restrict__ Vf)
{
    __shared__ u16 Alds[128 * 64];
    __shared__ u16 Blds[128 * 64];
    const int d = blockIdx.x;
    if (d < 128) {
        gemm_body<1>(d * 128, 0, xb, Wqb, Wkb, 64, Qf, Kf, Alds, Blds);
    } else {
        const int dd = d - 128;
        gemm_body<2>((dd >> 7) * 128, (dd & 127) * 128, Wvb, xb, xb, 1 << 30,
                     Vf, nullptr, Alds, Blds);
    }
}

// ----------------------------------------------------------------------------
// Flash attention, no-max softmax, es-split P handoff, software-pipelined.
// grid (128,4) flat d: g=d>>4, qt = g<16 ? 31-g : g-16 (complementary pairs),
// e0 = ((d>>2)&3)*256, b = d&3. Block 1024 thr (16 waves): wave w ->
// qs=w>>1 (16 q rows), es=w&1 (32 of the 64 s-cols in computeP; 128 e cols
// in PV). s-tile = 64: ntiles = 2qt+2. Iter order: barrier -> stageV(it+1)
// -> loadK(it+1) -> PV(it) -> computeP(it+1).
// ----------------------------------------------------------------------------
__global__ __launch_bounds__(1024, 4) void attn_fa(
    const u16* __restrict__ Qf,
    const u16* __restrict__ Kf,
    const u16* __restrict__ Vf,
    float* __restrict__ Out)
{
    __shared__ u16 Vlds[2][32 * 512];   // 2 x 32KB (e=256, s=64)
    __shared__ u16 Plds[2][128 * 72];   // 2 x 18KB block-shared P, row-pad 72

    const int tid  = threadIdx.x;
    const int lane = tid & 63, w = tid >> 6;      // w in [0,16)
    const int quad = lane >> 4, l15 = lane & 15;

    const int d  = blockIdx.y * 128 + blockIdx.x;
    const int g  = d >> 4;
    const int qt = (g < 16) ? (31 - g) : (g - 16);
    const int e0 = ((d >> 2) & 3) * 256;
    const int b  = d & 3;
    const int bt0 = b * 4096;

    const int qs = w >> 1, es = w & 1;            // qs in [0,8): 16 rows each
    const int qrow0 = qt * 128 + qs * 16;

    // Q A-frags (persistent, log2-domain scaled): one 16-row tile, K=64
    bf16x8 qf[2];
    {
        const int btile = (bt0 + qrow0) >> 4;
#pragma unroll
        for (int kk = 0; kk < 2; ++kk)
            qf[kk] = *(const bf16x8*)&Qf[(size_t)(btile * 2 + kk) * 512 + lane * 8];
    }

    // ones B-fragment for row-sum accumulation (bf16 1.0 = 0x3F80)
    const short o = (short)0x3F80;
    const bf16x8 ones = {o, o, o, o, o, o, o, o};

    f32x4 acc[8] = {};      // O accumulator [nb_e]
    f32x4 accl = {};        // row-sum accumulator

    const int ntiles = 2 * qt + 2;      // s-tiles of 64
    const int qlim = qrow0 + 15;        // wave active for tile it iff it*64 <= qlim

    // ---- stage V tile `it` (64 s-cols) into Vlds[buf]: 2KB per wave ----
    auto stageV = [&](int buf, int it) {
        const int ct0 = (bt0 >> 5) + it * 2;
#pragma unroll
        for (int h = 0; h < 2; ++h)
            g2lds16(&Vf[(size_t)(((e0 >> 4) + w) * 512 + ct0 + h) * 512 + lane * 8],
                    &Vlds[buf][(h * 16 + w) * 512]);
    };

    // ---- load this wave's K quarter for tile `jt` (4 x b128 global) ----
    auto loadK = [&](int jt, bf16x8* kf) {
#pragma unroll
        for (int cc = 0; cc < 2; ++cc)
#pragma unroll
            for (int kk = 0; kk < 2; ++kk) {
                const int kt = ((bt0 + jt * 64 + es * 32 + cc * 16) >> 4) * 2 + kk;
                kf[cc * 2 + kk] = *(const bf16x8*)&Kf[(size_t)kt * 512 + lane * 8];
            }
    };

    // ---- compute this wave's (16q x 32s) strip of P(jt) into Plds[jt&1] ----
    auto computeP = [&](int jt, const bf16x8* kf) {
        const int s0 = jt * 64;
#pragma unroll
        for (int cc = 0; cc < 2; ++cc) {
            f32x4 sf = {};
#pragma unroll
            for (int kk = 0; kk < 2; ++kk)
                sf = __builtin_amdgcn_mfma_f32_16x16x32_bf16(
                    qf[kk], kf[cc * 2 + kk], sf, 0, 0, 0);
            const int c0 = s0 + es * 32 + cc * 16;
            if (c0 + 15 > qrow0) {      // diagonal-crossing: mask
                const int colabs = c0 + l15;
#pragma unroll
                for (int r = 0; r < 4; ++r) {
                    const int rowabs = qrow0 + quad * 4 + r;
                    sf[r] = (colabs <= rowabs) ? sf[r] : -__builtin_inff();
                }
            }
            u16* Pl = &Plds[jt & 1][(qs * 16 + quad * 4) * 72 + es * 32 + cc * 16 + l15];
            const u32 p01 = pkbf(exp2f(sf[0]), exp2f(sf[1]));
            const u32 p23 = pkbf(exp2f(sf[2]), exp2f(sf[3]));
            Pl[0]   = (u16)p01;
            Pl[72]  = (u16)(p01 >> 16);
            Pl[144] = (u16)p23;
            Pl[216] = (u16)(p23 >> 16);
        }
    };

    // ---- prologue: tile 0 ----
    stageV(0, 0);
    {
        bf16x8 kf0[4];
        loadK(0, kf0);
        computeP(0, kf0);
    }

    for (int it = 0; it < ntiles; ++it) {
        __syncthreads();                 // V(it), P(it) ready (vmcnt drained)
        const int buf = it & 1;
        const bool haveNext = (it + 1 < ntiles);
        const bool nextActive = haveNext && ((it + 1) * 64 <= qlim);
        const bool curActive = (it * 64 <= qlim);

        if (haveNext) stageV(buf ^ 1, it + 1);
        bf16x8 kf[4];
        if (nextActive) loadK(it + 1, kf);

        if (curActive) {
            // ---- O += P @ V ; l += P @ 1 ---- (two s-halves h)
#pragma unroll
            for (int h = 0; h < 2; ++h) {
                const bf16x8 pf = *(const bf16x8*)
                    &Plds[buf][(qs * 16 + l15) * 72 + h * 32 + quad * 8];
                accl = __builtin_amdgcn_mfma_f32_16x16x32_bf16(pf, ones, accl, 0, 0, 0);
#pragma unroll
                for (int nb = 0; nb < 8; ++nb) {
                    bf16x8 vf = *(const bf16x8*)
                        &Vlds[buf][(h * 16 + es * 8 + nb) * 512 + lane * 8];
                    acc[nb] = __builtin_amdgcn_mfma_f32_16x16x32_bf16(
                        pf, vf, acc[nb], 0, 0, 0);
                }
            }
        }

        if (nextActive) computeP(it + 1, kf);
    }

    // ---- epilogue: normalize by row sums ----
    float rl[4];
#pragma unroll
    for (int r = 0; r < 4; ++r) rl[r] = 1.0f / accl[r];
#pragma unroll
    for (int nb = 0; nb < 8; ++nb)
#pragma unroll
        for (int r = 0; r < 4; ++r) {
            const int row = qrow0 + quad * 4 + r;
            const int col = e0 + es * 128 + nb * 16 + l15;
            Out[(size_t)(bt0 + row) * 1024 + col] = acc[nb][r] * rl[r];
        }
}

// ----------------------------------------------------------------------------
extern "C" void kernel_launch(void* const* d_in, const int* in_sizes, int n_in,
                              void* d_out, int out_size, void* d_ws, size_t ws_size,
                              hipStream_t stream) {
    const float* x  = (const float*)d_in[0];   // [4,4096,1024]
    const float* Wk = (const float*)d_in[1];   // [64,1024]
    const float* Wq = (const float*)d_in[2];   // [64,1024]
    const float* Wv = (const float*)d_in[3];   // [1024,1024]

    const int nx  = in_sizes[0];
    const int nwk = in_sizes[1];
    const int nwq = in_sizes[2];
    const int nwv = in_sizes[3];

    u16* xb  = (u16*)d_ws;
    u16* Wkb = xb  + (size_t)nx;
    u16* Wqb = Wkb + (size_t)nwk;
    u16* Wvb = Wqb + (size_t)nwq;
    u16* Qf  = Wvb + (size_t)nwv;                    // 1024 btiles * 2 * 512
    u16* Kf  = Qf  + (size_t)1024 * 2 * 512;
    u16* Vf  = Kf  + (size_t)1024 * 2 * 512;         // 64 etiles * 512 * 512
    float* out = (float*)d_out;

    const float qscale = 0.125f * 1.44269504088896f; // fold 1/sqrt(H)*log2(e)

    cvt_x<<<nx / 2048, 256, 0, stream>>>(x, xb, nx);
    cvt_w<<<(nwk + nwq + nwv) / 2048, 256, 0, stream>>>(Wk, Wq, Wv,
                                                        Wkb, Wqb, Wvb, qscale);

    gemm_all<<<1152, 256, 0, stream>>>(xb, Wqb, Wkb, Wvb, Qf, Kf, Vf);

    attn_fa<<<dim3(128, 4), 1024, 0, stream>>>(Qf, Kf, Vf, out);
}